// Round 8
// baseline (221.629 us; speedup 1.0000x reference)
//
#include <hip/hip_runtime.h>
#include <math.h>

#define Bn 32
#define Pn 256
#define Wn 16
#define Cn 64
#define Hn 128
#define PREDn 64
#define TOKn 17
#define TBLK 8

// async global->LDS: dest = wave-uniform lds base + lane*4
__device__ __forceinline__ void gload_lds(const float* g, float* l) {
  __builtin_amdgcn_global_load_lds(
      (const __attribute__((address_space(1))) unsigned int*)g,
      (__attribute__((address_space(3))) unsigned int*)l, 4, 0, 0);
}

// ---------------- Kernel A1: logstd anchor partials (8 t-slices x 32 b) ----------------
__global__ void lsa_part_kernel(const float* __restrict__ std_hist,
                                float* __restrict__ lsa_part) {
  int b = blockIdx.x;
  int ts = blockIdx.y;
  int c = threadIdx.x & 63;
  int q = threadIdx.x >> 6;
  const float* base = std_hist + ((size_t)b * Pn + ts * 32) * Cn + c;
  float s = 0.f;
#pragma unroll
  for (int i = 0; i < 8; ++i) {
    int t = q + 4 * i;
    s += logf(fmaxf(base[(size_t)t * Cn], 1e-3f));
  }
  __shared__ float red[4][64];
  red[q][c] = s;
  __syncthreads();
  if (q == 0) {
    lsa_part[ts * 2048 + b * 64 + c] = red[0][c] + red[1][c] + red[2][c] + red[3][c];
  }
}

__global__ void lsa_combine_kernel(const float* __restrict__ lsa_part,
                                   float* __restrict__ lsa) {
  int i = blockIdx.x * 256 + threadIdx.x;
  float v = 0.f;
#pragma unroll
  for (int k = 0; k < 8; ++k) v += lsa_part[k * 2048 + i];
  lsa[i] = v * (1.0f / 256.0f);
}

// ---------------- Kernel B: token matmul + EMA (hot kernel) ----------------
// Feature-major LDS staged via async global_load_lds (m97 pattern):
//   tokf[buf][row][k][32c]: one 64-lane inst fills feature rows k and k+1
//   (lanes 0-31 -> [k][0..31], lanes 32-63 -> [k+1][0..31] by linear-dest rule).
// No ds_writes, no register staging, no vmcnt stall before compute: loads for
// phase p+1 are issued async, COMPUTE(p) runs, __syncthreads drains.
// Uncentered tokens + no input bias (both telescoped; corrected in head).
// Std normalization at read time: u = (sum r*W)*inv - mu*inv*SW + logstd*W0
// (exact reassociation of ((r-mu)*inv) . W).
template <int NCH>
__launch_bounds__(256, 2)
__global__ void ema_kernel(
    const float* __restrict__ mu_hist, const float* __restrict__ std_hist,
    const float* __restrict__ raw,
    const float* __restrict__ mW, const float* __restrict__ mal,
    const float* __restrict__ sW, const float* __restrict__ sal,
    float* __restrict__ Spart) {
  constexpr int L = Pn / NCH;
  constexpr int NPH = L / TBLK;
  const int sx = blockIdx.x;  // 0..4*NCH-1
  const int cblk = sx & 1, hblk = (sx >> 1) & 1, ph = sx >> 2;
  const int b = blockIdx.y, br = blockIdx.z;
  const int tid = threadIdx.x;
  const int cr = tid & 31;
  const int w0 = tid >> 5;  // hh-group 0..7

  const float* inW = br ? sW : mW;
  const float* alog = br ? sal : mal;
  const int hh0 = hblk * 64 + w0 * 8;

  // Wr[k] = in_W row (1+k) for k=0..15 (raw feats); Wr[16] = row 0 (scalar feat)
  float Wr[TOKn][8];
#pragma unroll
  for (int k = 0; k < 16; ++k) {
    float4 a0 = *(const float4*)&inW[(1 + k) * Hn + hh0];
    float4 a1 = *(const float4*)&inW[(1 + k) * Hn + hh0 + 4];
    Wr[k][0] = a0.x; Wr[k][1] = a0.y; Wr[k][2] = a0.z; Wr[k][3] = a0.w;
    Wr[k][4] = a1.x; Wr[k][5] = a1.y; Wr[k][6] = a1.z; Wr[k][7] = a1.w;
  }
  {
    float4 a0 = *(const float4*)&inW[hh0];
    float4 a1 = *(const float4*)&inW[hh0 + 4];
    Wr[16][0] = a0.x; Wr[16][1] = a0.y; Wr[16][2] = a0.z; Wr[16][3] = a0.w;
    Wr[16][4] = a1.x; Wr[16][5] = a1.y; Wr[16][6] = a1.z; Wr[16][7] = a1.w;
  }
  float SW[8], av[8], h[8];
#pragma unroll
  for (int i = 0; i < 8; ++i) {
    float s = 0.f;
#pragma unroll
    for (int k = 0; k < 16; ++k) s += Wr[k][i];
    SW[i] = s;
    av[i] = 1.0f / (1.0f + expf(-alog[hh0 + i]));
    h[i] = 0.0f;
  }

  const int chalf = cblk * 32;
  const float* rawb = raw + ((size_t)b * Pn) * (Wn * Cn) + chalf;
  const float* mub = mu_hist + ((size_t)b * Pn) * Cn + chalf;
  const float* sdb = std_hist + ((size_t)b * Pn) * Cn + chalf;

  __shared__ float tokf[2][TBLK][16][32];  // 16 KB
  __shared__ float mu_l[2][TBLK][32];      // 2 KB
  __shared__ float sd_l[2][TBLK][32];      // 2 KB

  const int lane = tid & 63;
  const int wv = tid >> 6;   // wave 0..3 stages rows 2wv, 2wv+1
  const int lw = lane >> 5;  // half-wave selector
  const int lc = lane & 31;
  const int r0 = wv * 2;
  const int t0 = ph * L;

  auto ISSUE = [&](int tb, int buf) {
#pragma unroll
    for (int rr = 0; rr < 2; ++rr) {
      const int row = r0 + rr;
      const float* gb = rawb + (size_t)(tb + row) * (Wn * Cn);
#pragma unroll
      for (int k = 0; k < 16; k += 2) {
        gload_lds(gb + (k + lw) * Cn + lc, &tokf[buf][row][k][0]);
      }
    }
    gload_lds(mub + (size_t)(tb + r0 + lw) * Cn + lc, &mu_l[buf][r0][0]);
    if (br) gload_lds(sdb + (size_t)(tb + r0 + lw) * Cn + lc, &sd_l[buf][r0][0]);
  };

  auto COMPUTE = [&](int buf) {
#pragma unroll
    for (int r = 0; r < TBLK; ++r) {
      float tk[16];
#pragma unroll
      for (int k = 0; k < 16; ++k) tk[k] = tokf[buf][r][k][cr];
      float sc = mu_l[buf][r][cr];
      if (br == 0) {
#pragma unroll
        for (int i = 0; i < 8; ++i) {
          float u = tk[0] * Wr[0][i];
#pragma unroll
          for (int k = 1; k < 16; ++k) u = fmaf(tk[k], Wr[k][i], u);
          u = fmaf(sc, Wr[16][i], u);
          h[i] = fmaf(av[i], h[i] - u, u);  // a*h + (1-a)*u
        }
      } else {
        float sd = sd_l[buf][r][cr];
        float inv = 1.0f / (sd + 1e-5f);
        float ls = logf(fmaxf(sd, 1e-3f));
        float nmi = -sc * inv;
#pragma unroll
        for (int i = 0; i < 8; ++i) {
          float u = tk[0] * Wr[0][i];
#pragma unroll
          for (int k = 1; k < 16; ++k) u = fmaf(tk[k], Wr[k][i], u);
          u = u * inv;
          u = fmaf(nmi, SW[i], u);
          u = fmaf(ls, Wr[16][i], u);
          h[i] = fmaf(av[i], h[i] - u, u);
        }
      }
    }
  };

  ISSUE(t0, 0);
  __syncthreads();  // compiler drains vmcnt before barrier
  int cur = 0;
#pragma unroll 1
  for (int p = 0; p < NPH; ++p) {
    if (p + 1 < NPH) ISSUE(t0 + (p + 1) * TBLK, cur ^ 1);
    COMPUTE(cur);
    __syncthreads();
    cur ^= 1;
  }

  const int idx_block = (((br * NCH + ph) * Bn + b) * 2 + cblk) * 2 + hblk;
  float* op = Spart + (size_t)idx_block * 2048 + tid * 8;
  float4 o0 = {h[0], h[1], h[2], h[3]};
  float4 o1 = {h[4], h[5], h[6], h[7]};
  *(float4*)op = o0;
  *(float4*)(op + 4) = o1;
}

// ---------------- Kernel C: combine chunks + corrections + GELU-MLP head ----------------
// h = sum_k aL^(NCH-1-k)*h_k  - (1-a^P)*SW*shift  + (1-a^P)*in_bias
template <int G, int NCH>
__launch_bounds__(128, 4)
__global__ void head_kernel(
    const float* __restrict__ anchor, const float* __restrict__ lsa,
    const float* __restrict__ mW, const float* __restrict__ sW,
    const float* __restrict__ mIB, const float* __restrict__ sIB,
    const float* __restrict__ mal, const float* __restrict__ mpW, const float* __restrict__ mpb,
    const float* __restrict__ moW, const float* __restrict__ mob, const float* __restrict__ gmu,
    const float* __restrict__ sal, const float* __restrict__ spW, const float* __restrict__ spb,
    const float* __restrict__ soW, const float* __restrict__ sob, const float* __restrict__ gst,
    const float* __restrict__ Spart, float* __restrict__ out) {
  constexpr int L = Pn / NCH;
  const int br = blockIdx.y;
  const int bc0 = blockIdx.x * G;
  const int tid = threadIdx.x;  // 0..127 = hh
  const float* alog = br ? sal : mal;
  const float* pW = br ? spW : mpW;
  const float* pb = br ? spb : mpb;
  const float* oW = br ? soW : moW;
  const float* ob = br ? sob : mob;
  const float inb = br ? sIB[tid] : mIB[tid];

  __shared__ float smem[2 * G * 128];
  float* g_lds = smem;
  float* h2 = smem + G * 128;

  const float a = 1.0f / (1.0f + expf(-alog[tid]));
  float aL = a;
#pragma unroll
  for (int s7 = 0; s7 < 31 - __builtin_clz(L); ++s7) aL *= aL;
  float fac[NCH];
  fac[NCH - 1] = 1.0f;
#pragma unroll
  for (int k = NCH - 2; k >= 0; --k) fac[k] = fac[k + 1] * aL;
  const float apF = fac[0] * aL;  // a^Pn
  float SWv;
  if (br == 0) {
    float s = 0.f;
#pragma unroll
    for (int k = 0; k < TOKn; ++k) s += mW[k * Hn + tid];
    SWv = s;
  } else {
    SWv = sW[tid];
  }
  const float om = 1.0f - apF;
  const float cS = om * SWv;

  const int hblk = tid >> 6;
  const int hhg = (tid >> 3) & 7;
  const int ii = tid & 7;

  float hreg[G];
#pragma unroll
  for (int g = 0; g < G; ++g) {
    int bc = bc0 + g;
    int bb = bc >> 6, cc = bc & 63;
    int cblk2 = cc >> 5, crr = cc & 31;
    const size_t inner = (size_t)(hhg * 32 + crr) * 8 + ii;
    const int blk0 = (((br * NCH + 0) * Bn + bb) * 2 + cblk2) * 2 + hblk;
    float hv = 0.f;
#pragma unroll
    for (int k = 0; k < NCH; ++k) {
      hv = fmaf(fac[k], Spart[(size_t)(blk0 + k * (Bn * 4)) * 2048 + inner], hv);
    }
    float shiftv = br ? lsa[bb * Cn + cc] : anchor[bb * Cn + cc];
    hv = fmaf(-cS, shiftv, hv);  // centering correction
    hv = fmaf(om, inb, hv);      // telescoped input bias
    hreg[g] = hv;
    g_lds[g * 128 + tid] = 0.5f * hv * (1.0f + erff(hv * 0.70710678118654752f));
  }
  __syncthreads();

  float acc[G];
#pragma unroll
  for (int g = 0; g < G; ++g) acc[g] = hreg[g] + pb[tid];
  for (int j = 0; j < 128; j += 4) {
    float w0v = pW[j * Hn + tid];
    float w1v = pW[(j + 1) * Hn + tid];
    float w2v = pW[(j + 2) * Hn + tid];
    float w3v = pW[(j + 3) * Hn + tid];
#pragma unroll
    for (int g = 0; g < G; ++g) {
      float4 gv = *(const float4*)&g_lds[g * 128 + j];
      acc[g] = fmaf(gv.x, w0v, acc[g]);
      acc[g] = fmaf(gv.y, w1v, acc[g]);
      acc[g] = fmaf(gv.z, w2v, acc[g]);
      acc[g] = fmaf(gv.w, w3v, acc[g]);
    }
  }
#pragma unroll
  for (int g = 0; g < G; ++g) h2[g * 128 + tid] = acc[g];
  __syncthreads();

  const int p = tid & 63;
  const int jh = tid >> 6;
  float s[G];
#pragma unroll
  for (int g = 0; g < G; ++g) s[g] = 0.f;
  for (int jj = 0; jj < 64; jj += 4) {
    int j = jh * 64 + jj;
    float w0v = oW[j * PREDn + p];
    float w1v = oW[(j + 1) * PREDn + p];
    float w2v = oW[(j + 2) * PREDn + p];
    float w3v = oW[(j + 3) * PREDn + p];
#pragma unroll
    for (int g = 0; g < G; ++g) {
      float4 hv4 = *(const float4*)&h2[g * 128 + j];
      s[g] = fmaf(hv4.x, w0v, s[g]);
      s[g] = fmaf(hv4.y, w1v, s[g]);
      s[g] = fmaf(hv4.z, w2v, s[g]);
      s[g] = fmaf(hv4.w, w3v, s[g]);
    }
  }
  float* red = smem;
#pragma unroll
  for (int g = 0; g < G; ++g) red[jh * (G * 64) + g * 64 + p] = s[g];
  __syncthreads();
  if (tid < 64) {
#pragma unroll
    for (int g = 0; g < G; ++g) {
      int bc = bc0 + g;
      int bb = bc >> 6, cc = bc & 63;
      float tot = red[g * 64 + p] + red[G * 64 + g * 64 + p] + ob[p];
      if (br == 0) {
        out[((size_t)bb * PREDn + p) * Cn + cc] = fmaf(gmu[cc], tot, anchor[bb * Cn + cc]);
      } else {
        float lf = fmaf(gst[cc], tot, lsa[bb * Cn + cc]);
        out[131072 + ((size_t)bb * PREDn + p) * Cn + cc] = fmaxf(expf(lf), 1e-3f);
      }
    }
  }
}

extern "C" void kernel_launch(void* const* d_in, const int* in_sizes, int n_in,
                              void* d_out, int out_size, void* d_ws, size_t ws_size,
                              hipStream_t stream) {
  (void)in_sizes; (void)n_in; (void)out_size;
  const float* mu_hist = (const float*)d_in[0];
  const float* std_hist = (const float*)d_in[1];
  const float* anchor = (const float*)d_in[2];
  const float* raw = (const float*)d_in[3];
  const float* mW = (const float*)d_in[4];
  const float* mb_ = (const float*)d_in[5];
  const float* mal = (const float*)d_in[6];
  const float* mpW = (const float*)d_in[7];
  const float* mpb = (const float*)d_in[8];
  const float* moW = (const float*)d_in[9];
  const float* mob = (const float*)d_in[10];
  const float* gmu = (const float*)d_in[11];
  const float* sW = (const float*)d_in[12];
  const float* sb_ = (const float*)d_in[13];
  const float* sal = (const float*)d_in[14];
  const float* spW = (const float*)d_in[15];
  const float* spb = (const float*)d_in[16];
  const float* soW = (const float*)d_in[17];
  const float* sob = (const float*)d_in[18];
  const float* gst = (const float*)d_in[19];
  float* out = (float*)d_out;
  float* ws = (float*)d_ws;

  float* lsa = ws;                  // 2048 floats
  float* lsa_part = ws + 2048;      // 8*2048 floats
  float* Spart = ws + 2048 + 16384; // up to 1024*2048 floats (NCH=4)

  const size_t need4 = (size_t)(2048 + 16384 + 1024 * 2048) * 4;

  hipLaunchKernelGGL(lsa_part_kernel, dim3(32, 8), dim3(256), 0, stream, std_hist, lsa_part);
  hipLaunchKernelGGL(lsa_combine_kernel, dim3(8), dim3(256), 0, stream, lsa_part, lsa);
  if (ws_size >= need4) {
    hipLaunchKernelGGL(HIP_KERNEL_NAME(ema_kernel<4>), dim3(16, 32, 2), dim3(256), 0, stream,
                       mu_hist, std_hist, raw, mW, mal, sW, sal, Spart);
    hipLaunchKernelGGL(HIP_KERNEL_NAME(head_kernel<2, 4>), dim3(1024, 2), dim3(128), 0, stream,
                       anchor, lsa, mW, sW, mb_, sb_, mal, mpW, mpb, moW, mob, gmu,
                       sal, spW, spb, soW, sob, gst, Spart, out);
  } else {
    hipLaunchKernelGGL(HIP_KERNEL_NAME(ema_kernel<2>), dim3(8, 32, 2), dim3(256), 0, stream,
                       mu_hist, std_hist, raw, mW, mal, sW, sal, Spart);
    hipLaunchKernelGGL(HIP_KERNEL_NAME(head_kernel<2, 2>), dim3(1024, 2), dim3(128), 0, stream,
                       anchor, lsa, mW, sW, mb_, sb_, mal, mpW, mpb, moW, mob, gmu,
                       sal, spW, spb, soW, sob, gst, Spart, out);
  }
}